// Round 6
// baseline (93.519 us; speedup 1.0000x reference)
//
#include <hip/hip_runtime.h>

// out[s,i] = Re( U x_s ), reverse-order transposed-gate statevector sim.
// Per reversed layer: [composed ring-CNOT perm sigma, folded into pass-A read
// indices] then 10 commuting U3^T gates split 5|5:
//   pass A: bits 5-9 in registers (thread = low-5 bits), 5 butterfly levels
//   pass B: bits 0-4 in registers (thread = high-5 bits), 5 butterfly levels
// -> 2 LDS round-trips per layer instead of 5. Qubit q <-> bit (9-q).
// LDS float2 with XOR swizzle k^(((k>>5)&15)<<1) (even mask: preserves pair
// contiguity) + 4-complex per-sv pad. Layer-0 pass-B stores registers->global.
// R6 fix: init scatter used p>>1 + 1 for the (k+2,k+3) pair; correct address
// is swz(k+2) = swz(k)^2 (differs when bit3 of lane set) — was scrambling
// half the lanes' initial state.

#define NQ 10
#define NL 5
#define NST 1024
#define NTH 64            // 1 wave per block, 2 statevectors
#define SV_STRIDE 1028    // complex; pad 4 -> +8 bank shift for sv1

// Composed reversed-CNOT permutation (temporal chain, q=0 step first).
// Verified in rounds 3/4. GF(2)-linear.
constexpr int csigma(int i) {
  for (int q = 0; q < NQ; ++q) {
    const int cb = 9 - q, tb = 9 - ((q + 1) % NQ);
    i ^= ((i >> cb) & 1) << tb;
  }
  return i;
}

__device__ __forceinline__ int swz(int k) { return k ^ (((k >> 5) & 15) << 1); }

__global__ void build_gates(const float* __restrict__ w, float* __restrict__ gw) {
  const int t = threadIdx.x;
  if (t < NL * NQ) {
    const float th = w[t * 3 + 0], ph = w[t * 3 + 1], lm = w[t * 3 + 2];
    const float ch = cosf(0.5f * th), sh = sinf(0.5f * th);
    const float cl = cosf(lm), sl = sinf(lm);
    const float cp = cosf(ph), sp = sinf(ph);
    const float cpl = cosf(ph + lm), spl = sinf(ph + lm);
    float* G = gw + t * 8;  // transposed U3: h01=g10, h10=g01; h00 real
    G[0] = ch;       G[1] = 0.0f;
    G[2] = cp * sh;  G[3] = sp * sh;
    G[4] = -cl * sh; G[5] = -sl * sh;
    G[6] = cpl * ch; G[7] = spl * ch;
  }
}

// (a,b) <- H (a,b); h00 is real (imag statically 0) -> 14 FMAs not 16.
__device__ __forceinline__ void bfly(float2& a, float2& b, const float h00,
                                     const float2 h01, const float2 h10,
                                     const float2 h11) {
  const float nar = h00 * a.x + h01.x * b.x - h01.y * b.y;
  const float nai = h00 * a.y + h01.x * b.y + h01.y * b.x;
  const float nbr = h10.x * a.x - h10.y * a.y + h11.x * b.x - h11.y * b.y;
  const float nbi = h10.x * a.y + h10.y * a.x + h11.x * b.y + h11.y * b.x;
  a = make_float2(nar, nai);
  b = make_float2(nbr, nbi);
}

__global__ __launch_bounds__(NTH) void qc_apply(
    const float* __restrict__ x, const float* __restrict__ gw,
    float* __restrict__ out, int out_size) {
  __shared__ float2 sc[2 * SV_STRIDE];

  const int t = threadIdx.x;
  const int lane = t & 31;          // lane within statevector
  const int svLocal = t >> 5;       // 0 or 1
  const int svGlobal = blockIdx.x * 2 + svLocal;
  const int svo = svLocal * SV_STRIDE;
  float4* const s4 = (float4*)(sc + svo);

  // ---- init: coalesced global float4 loads -> swizzled LDS (imag = 0).
  // Pair (k,k+1) -> physical complex swz(k) (even); pair (k+2,k+3) ->
  // physical swz(k+2) = swz(k)^2. Both 16B-aligned float4 stores.
  {
    const float* xs = x + (size_t)svGlobal * NST;
#pragma unroll
    for (int r = 0; r < 8; ++r) {
      const int k = lane * 4 + 128 * r;      // 4 consecutive complex indices
      const float4 xv = *(const float4*)(xs + k);
      const int p01 = swz(k);                // even
      const int p23 = p01 ^ 2;               // = swz(k+2)
      *(float4*)&sc[svo + p01] = make_float4(xv.x, 0.f, xv.y, 0.f);
      *(float4*)&sc[svo + p23] = make_float4(xv.z, 0.f, xv.w, 0.f);
    }
  }
  __syncthreads();

  // sigma images: low-bit part (runtime, linear in lane) + high-bit constants.
  int sL = lane;
#pragma unroll
  for (int q = 0; q < NQ; ++q) {
    const int cb = 9 - q, tb = 9 - ((q + 1) % NQ);
    sL ^= ((sL >> cb) & 1) << tb;
  }
  constexpr int SH0 = csigma(1 << 5), SH1 = csigma(1 << 6),
                SH2 = csigma(1 << 7), SH3 = csigma(1 << 8),
                SH4 = csigma(1 << 9);

  const int m = (lane & 15) << 1;  // pass-B swizzle mask for this thread
  float2 w2[32];                   // pass-B register states (live at exit)

#pragma unroll 1
  for (int l = NL - 1; l >= 0; --l) {
    const float* gl = gw + l * NQ * 8;

    // ======== pass A: sigma-gather; bits 5-9 live in register index j.
    float2 v[32];
#pragma unroll
    for (int j = 0; j < 32; ++j) {
      const int idx = sL ^ ((j & 1) ? SH0 : 0) ^ ((j & 2) ? SH1 : 0) ^
                      ((j & 4) ? SH2 : 0) ^ ((j & 8) ? SH3 : 0) ^
                      ((j & 16) ? SH4 : 0);
      v[j] = sc[svo + swz(idx)];
    }
    // 5 butterfly levels: bit (5+e) <-> qubit (4-e).
#pragma unroll
    for (int e = 0; e < 5; ++e) {
      const float* G = gl + (4 - e) * 8;
      const float h00 = G[0];
      const float2 h01 = make_float2(G[2], G[3]);
      const float2 h10 = make_float2(G[4], G[5]);
      const float2 h11 = make_float2(G[6], G[7]);
#pragma unroll
      for (int j = 0; j < 32; ++j)
        if (!(j & (1 << e))) bfly(v[j], v[j | (1 << e)], h00, h01, h10, h11);
    }
    __syncthreads();  // all sigma-gathers complete before overwriting
#pragma unroll
    for (int j = 0; j < 32; ++j)
      sc[svo + swz((j << 5) | lane)] = v[j];
    __syncthreads();

    // ======== pass B: contiguous; bits 0-4 live in register index i.
#pragma unroll
    for (int a = 0; a < 16; ++a) {
      const float4 p = s4[((lane << 5) + ((2 * a) ^ m)) >> 1];
      w2[2 * a]     = make_float2(p.x, p.y);
      w2[2 * a + 1] = make_float2(p.z, p.w);
    }
    // 5 butterfly levels: bit e <-> qubit (9-e).
#pragma unroll
    for (int e = 0; e < 5; ++e) {
      const float* G = gl + (9 - e) * 8;
      const float h00 = G[0];
      const float2 h01 = make_float2(G[2], G[3]);
      const float2 h10 = make_float2(G[4], G[5]);
      const float2 h11 = make_float2(G[6], G[7]);
#pragma unroll
      for (int i = 0; i < 32; ++i)
        if (!(i & (1 << e))) bfly(w2[i], w2[i | (1 << e)], h00, h01, h10, h11);
    }
    if (l != 0) {
#pragma unroll
      for (int a = 0; a < 16; ++a)
        s4[((lane << 5) + ((2 * a) ^ m)) >> 1] =
            make_float4(w2[2 * a].x, w2[2 * a].y, w2[2 * a + 1].x, w2[2 * a + 1].y);
      __syncthreads();
    }
  }

  // ---- layer-0 pass-B results go straight from registers to global (reals).
  const size_t ob = (size_t)svGlobal * NST + (lane << 5);
#pragma unroll
  for (int a = 0; a < 8; ++a) {
    if (ob + 4 * a + 4 <= (size_t)out_size)
      *(float4*)(out + ob + 4 * a) =
          make_float4(w2[4 * a].x, w2[4 * a + 1].x, w2[4 * a + 2].x, w2[4 * a + 3].x);
  }
}

extern "C" void kernel_launch(void* const* d_in, const int* in_sizes, int n_in,
                              void* d_out, int out_size, void* d_ws, size_t ws_size,
                              hipStream_t stream) {
  const float* x = (const float*)d_in[0];   // [128,16,32,32] f32
  const float* w = (const float*)d_in[1];   // [5,10,3] f32
  float* out = (float*)d_out;               // f32 (real part of complex64)
  float* gw = (float*)d_ws;                 // 50 gates x 8 floats = 1600 B
  const int nstates = in_sizes[0] / NST;    // 2048
  build_gates<<<1, 64, 0, stream>>>(w, gw);
  qc_apply<<<nstates / 2, NTH, 0, stream>>>(x, gw, out, out_size);
}

// Round 8
// 85.010 us; speedup vs baseline: 1.1001x; 1.1001x over previous
//
#include <hip/hip_runtime.h>

// out[s,i] = Re( U x_s ), reverse-order transposed-gate statevector sim.
// 16 states/thread, 64 lanes per SV, 1 wave = 1 SV -> 2048 waves = 2/SIMD.
// Per reversed layer, three register passes (10 gates, qubit q <-> bit 9-q):
//   A: regs = bits 6-9 (gates q=3..0), sigma (composed ring-CNOT) folded into
//      the gather reads;
//   C: regs = bits 4-7 layout, apply gates on bits 4,5 (q=5,4);
//   B: regs = bits 0-3 (gates q=9..6), b128 LDS access; layer-0 streams
//      registers -> global (reals only).
// LDS: one SV (1024 f2 = 8 KB), swizzle k ^ (((k>>4)&7)<<1).
// Convention: logical k lives at phys swz(k); phys (t<<4)|j holds logical
// (t<<4)|(j^m), m=(t&7)<<1.
// R8 fix (vs R7): pass-B read assigned phys pair (2rp)^m to v[(2rp)^m];
// correct register label is the LOGICAL index 2rp (R6's passing convention).

#define NQ 10
#define NL 5
#define NST 1024
#define NTH 64

typedef float f2 __attribute__((ext_vector_type(2)));

// Composed reversed-CNOT permutation (temporal chain, q=0 step first).
// Verified rounds 3/4/6. GF(2)-linear.
constexpr int csigma(int i) {
  for (int q = 0; q < NQ; ++q) {
    const int cb = 9 - q, tb = 9 - ((q + 1) % NQ);
    i ^= ((i >> cb) & 1) << tb;
  }
  return i;
}

__device__ __forceinline__ int swz(int k) { return k ^ (((k >> 4) & 7) << 1); }

__global__ void build_gates(const float* __restrict__ w, float* __restrict__ gw) {
  const int t = threadIdx.x;
  if (t < NL * NQ) {
    const float th = w[t * 3 + 0], ph = w[t * 3 + 1], lm = w[t * 3 + 2];
    const float ch = cosf(0.5f * th), sh = sinf(0.5f * th);
    const float cl = cosf(lm), sl = sinf(lm);
    const float cp = cosf(ph), sp = sinf(ph);
    const float cpl = cosf(ph + lm), spl = sinf(ph + lm);
    float* G = gw + t * 8;  // transposed U3: h01=g10, h10=g01; h00 real
    G[0] = ch;       G[1] = 0.0f;
    G[2] = cp * sh;  G[3] = sp * sh;
    G[4] = -cl * sh; G[5] = -sl * sh;
    G[6] = cpl * ch; G[7] = spl * ch;
  }
}

// (a,b) <- H (a,b), h00 real. i*z = (-z.y, z.x); h01*b = h01x*b + h01y*(i*b).
__device__ __forceinline__ void bfly(f2& a, f2& b, const float h00,
                                     const float h01x, const float h01y,
                                     const float h10x, const float h10y,
                                     const float h11x, const float h11y) {
  const f2 ia = (f2){-a.y, a.x};
  const f2 ib = (f2){-b.y, b.x};
  const f2 na = h00 * a + h01x * b + h01y * ib;
  const f2 nb = h10x * a + h10y * ia + h11x * b + h11y * ib;
  a = na;
  b = nb;
}

#define LOAD_G(G)                                             \
  const float h00 = (G)[0];                                   \
  const float h01x = (G)[2], h01y = (G)[3];                   \
  const float h10x = (G)[4], h10y = (G)[5];                   \
  const float h11x = (G)[6], h11y = (G)[7];

__global__ __launch_bounds__(NTH) void qc_apply(
    const float* __restrict__ x, const float* __restrict__ gw,
    float* __restrict__ out, int out_size) {
  __shared__ alignas(16) f2 sc[NST];

  const int t = threadIdx.x;          // 64 lanes = SV bits per pass layout
  const int sv = blockIdx.x;
  const int m = (t & 7) << 1;         // swizzle mask when k>>4 == t

  // ---- init: 16 consecutive reals per thread -> logical (t<<4 | j), imag 0.
  {
    const float* xs = x + (size_t)sv * NST;
#pragma unroll
    for (int jp = 0; jp < 4; ++jp) {
      const float4 xv = ((const float4*)xs)[t * 4 + jp];
      const int j0 = (jp * 4) ^ m;          // phys of logical jp*4; even
      *(float4*)&sc[(t << 4) | j0]       = make_float4(xv.x, 0.f, xv.y, 0.f);
      *(float4*)&sc[(t << 4) | (j0 ^ 2)] = make_float4(xv.z, 0.f, xv.w, 0.f);
    }
  }
  __syncthreads();

  // sigma: runtime image of the 6 low bits + constexpr images of bits 6-9.
  int sL = t;
#pragma unroll
  for (int q = 0; q < NQ; ++q) {
    const int cb = 9 - q, tb = 9 - ((q + 1) % NQ);
    sL ^= ((sL >> cb) & 1) << tb;
  }
  constexpr int SH6 = csigma(1 << 6), SH7 = csigma(1 << 7),
                SH8 = csigma(1 << 8), SH9 = csigma(1 << 9);

  f2 v[16];

#pragma unroll 1
  for (int l = NL - 1; l >= 0; --l) {
    const float* gl = gw + l * NQ * 8;

    // ======== pass A: sigma-gather; regs = bits 6-9, thread = bits 0-5.
#pragma unroll
    for (int r = 0; r < 16; ++r) {
      const int idx = sL ^ ((r & 1) ? SH6 : 0) ^ ((r & 2) ? SH7 : 0) ^
                      ((r & 4) ? SH8 : 0) ^ ((r & 8) ? SH9 : 0);
      v[r] = sc[swz(idx)];
    }
#pragma unroll
    for (int e = 0; e < 4; ++e) {   // bit 6+e <-> qubit 3-e
      LOAD_G(gl + (3 - e) * 8)
#pragma unroll
      for (int r = 0; r < 16; ++r)
        if (!(r & (1 << e)))
          bfly(v[r], v[r | (1 << e)], h00, h01x, h01y, h10x, h10y, h11x, h11y);
    }
    __syncthreads();
#pragma unroll
    for (int r = 0; r < 16; ++r) sc[swz((r << 6) | t)] = v[r];
    __syncthreads();

    // ======== pass C: regs = bits 4-7, thread = bits 0-3 & 8-9; gates bits 4,5.
    const int cbase = ((t >> 4) << 8) | (t & 15);
#pragma unroll
    for (int r = 0; r < 16; ++r) v[r] = sc[swz(cbase | (r << 4))];
#pragma unroll
    for (int e = 0; e < 2; ++e) {   // bit 4+e <-> qubit 5-e
      LOAD_G(gl + (5 - e) * 8)
#pragma unroll
      for (int r = 0; r < 16; ++r)
        if (!(r & (1 << e)))
          bfly(v[r], v[r | (1 << e)], h00, h01x, h01y, h10x, h10y, h11x, h11y);
    }
    __syncthreads();
#pragma unroll
    for (int r = 0; r < 16; ++r) sc[swz(cbase | (r << 4))] = v[r];
    __syncthreads();

    // ======== pass B: regs = bits 0-3, thread = bits 4-9; b128 access.
    // phys pair (2rp)^m holds logical pair 2rp (swz involution on bits 1-3).
#pragma unroll
    for (int rp = 0; rp < 8; ++rp) {
      const float4 p = *(const float4*)&sc[(t << 4) | ((2 * rp) ^ m)];
      v[2 * rp]     = (f2){p.x, p.y};
      v[2 * rp + 1] = (f2){p.z, p.w};
    }
#pragma unroll
    for (int e = 0; e < 4; ++e) {   // bit e <-> qubit 9-e
      LOAD_G(gl + (9 - e) * 8)
#pragma unroll
      for (int r = 0; r < 16; ++r)
        if (!(r & (1 << e)))
          bfly(v[r], v[r | (1 << e)], h00, h01x, h01y, h10x, h10y, h11x, h11y);
    }
    if (l != 0) {
      // store logical pair 2rp back to phys pair (2rp)^m
#pragma unroll
      for (int rp = 0; rp < 8; ++rp) {
        *(float4*)&sc[(t << 4) | ((2 * rp) ^ m)] =
            make_float4(v[2 * rp].x, v[2 * rp].y,
                        v[2 * rp + 1].x, v[2 * rp + 1].y);
      }
      __syncthreads();
    }
  }

  // ---- layer-0 pass-B results: registers -> global (reals), coalesced.
  const size_t ob = (size_t)sv * NST + (t << 4);
#pragma unroll
  for (int rp = 0; rp < 4; ++rp) {
    if (ob + 4 * rp + 4 <= (size_t)out_size)
      *(float4*)(out + ob + 4 * rp) =
          make_float4(v[4 * rp].x, v[4 * rp + 1].x,
                      v[4 * rp + 2].x, v[4 * rp + 3].x);
  }
}

extern "C" void kernel_launch(void* const* d_in, const int* in_sizes, int n_in,
                              void* d_out, int out_size, void* d_ws, size_t ws_size,
                              hipStream_t stream) {
  const float* x = (const float*)d_in[0];   // [128,16,32,32] f32
  const float* w = (const float*)d_in[1];   // [5,10,3] f32
  float* out = (float*)d_out;               // f32 (real part of complex64)
  float* gw = (float*)d_ws;                 // 50 gates x 8 floats = 1600 B
  const int nstates = in_sizes[0] / NST;    // 2048
  build_gates<<<1, 64, 0, stream>>>(w, gw);
  qc_apply<<<nstates, NTH, 0, stream>>>(x, gw, out, out_size);
}